// Round 4
// baseline (125.711 us; speedup 1.0000x reference)
//
#include <hip/hip_runtime.h>

#define CONS_RATE 0.001f
#define CLAMP_V   10.0f

typedef float v4f __attribute__((ext_vector_type(4)));  // clang vector: valid for nontemporal builtins

// Per-element: out = clamp(w + 0.001*tanh(b2 + sum_j w2_j * relu(a_j*w + c_j)))
// with a_j = W1[0][j], c_j = cs*W1[1][j] + fs*W1[2][j] + b1[j] (wave-uniform).

__global__ __launch_bounds__(256) void ConsolidationDynamics_70068096467285_kernel(
    const float* __restrict__ w,
    const float* __restrict__ cs_p,
    const float* __restrict__ fs_p,
    const float* __restrict__ W1,   // (3,16) row-major
    const float* __restrict__ b1,   // (16,)
    const float* __restrict__ W2,   // (16,1)
    const float* __restrict__ b2,   // (1,)
    float* __restrict__ out,
    int n)
{
    const float cs  = cs_p[0];
    const float fs  = fs_p[0];
    const float bb2 = b2[0];

#define COEF(J) \
    const float a##J = W1[J]; \
    const float c##J = fmaf(cs, W1[16 + J], fmaf(fs, W1[32 + J], b1[J])); \
    const float v##J = W2[J];
    COEF(0)  COEF(1)  COEF(2)  COEF(3)
    COEF(4)  COEF(5)  COEF(6)  COEF(7)
    COEF(8)  COEF(9)  COEF(10) COEF(11)
    COEF(12) COEF(13) COEF(14) COEF(15)
#undef COEF

#define TERM(J, r, s) { float h = fmaf((r), a##J, c##J); h = fmaxf(h, 0.0f); (s) = fmaf(h, v##J, (s)); }
#define EVAL(r, d) { \
    float s = bb2; \
    TERM(0,(r),s)  TERM(1,(r),s)  TERM(2,(r),s)  TERM(3,(r),s)  \
    TERM(4,(r),s)  TERM(5,(r),s)  TERM(6,(r),s)  TERM(7,(r),s)  \
    TERM(8,(r),s)  TERM(9,(r),s)  TERM(10,(r),s) TERM(11,(r),s) \
    TERM(12,(r),s) TERM(13,(r),s) TERM(14,(r),s) TERM(15,(r),s) \
    float e  = __expf(2.0f * s); \
    float u  = 1.0f - 2.0f * __builtin_amdgcn_rcpf(e + 1.0f); \
    float nw = fmaf(u, CONS_RATE, (r)); \
    (d) = fminf(fmaxf(nw, -CLAMP_V), CLAMP_V); }

    const int n4 = n >> 2;
    const v4f* __restrict__ w4 = (const v4f*)w;
    v4f* __restrict__ o4 = (v4f*)out;

    const int nthreads = gridDim.x * blockDim.x;
    const int tid      = blockIdx.x * blockDim.x + threadIdx.x;
    const int step     = nthreads * 2;

    int i0 = tid;
    int i1 = tid + nthreads;

    // 2 float4 (8 elems) per thread: enough ILP, small VGPR footprint.
    for (; i1 < n4; i0 += step, i1 += step) {
        const v4f A = w4[i0];
        const v4f B = w4[i1];
        v4f oA, oB;
        EVAL(A.x, oA.x) EVAL(A.y, oA.y) EVAL(A.z, oA.z) EVAL(A.w, oA.w)
        EVAL(B.x, oB.x) EVAL(B.y, oB.y) EVAL(B.z, oB.z) EVAL(B.w, oB.w)
        __builtin_nontemporal_store(oA, &o4[i0]);   // streaming store: skip cache allocate
        __builtin_nontemporal_store(oB, &o4[i1]);
    }
    for (; i0 < n4; i0 += nthreads) {
        const v4f A = w4[i0];
        v4f oA;
        EVAL(A.x, oA.x) EVAL(A.y, oA.y) EVAL(A.z, oA.z) EVAL(A.w, oA.w)
        __builtin_nontemporal_store(oA, &o4[i0]);
    }
    // Scalar tail (n % 4) — not hit for 4096x4096.
    for (int i = (n4 << 2) + tid; i < n; i += nthreads) {
        const float r = w[i];
        float d;
        EVAL(r, d)
        out[i] = d;
    }
#undef EVAL
#undef TERM
}

extern "C" void kernel_launch(void* const* d_in, const int* in_sizes, int n_in,
                              void* d_out, int out_size, void* d_ws, size_t ws_size,
                              hipStream_t stream) {
    const float* w   = (const float*)d_in[0];
    const float* cs  = (const float*)d_in[1];
    const float* fs  = (const float*)d_in[2];
    const float* W1  = (const float*)d_in[3];
    const float* b1  = (const float*)d_in[4];
    const float* W2  = (const float*)d_in[5];
    const float* b2  = (const float*)d_in[6];
    float* out = (float*)d_out;

    const int n = in_sizes[0];
    // n4 = 4.19M float4s; 8192 blocks x 256 threads x 2 float4 covers exactly.
    const int block = 256;
    const int grid  = 8192;

    ConsolidationDynamics_70068096467285_kernel<<<grid, block, 0, stream>>>(
        w, cs, fs, W1, b1, W2, b2, out, n);
}